// Round 1
// baseline (28015.607 us; speedup 1.0000x reference)
//
#include <hip/hip_runtime.h>

#define N_NODES 500000
#define N_EDGES 16000000

// ---------------- degree ----------------
__global__ void deg_kernel(const int* __restrict__ dst, int* __restrict__ deg) {
    int i = blockIdx.x * blockDim.x + threadIdx.x;
    if (i < N_EDGES) {
        atomicAdd(&deg[dst[i]], 1);
    }
}

// ---------------- edge scatter-add (mean numerator) ----------------
template <int F>
__global__ void edge_agg(const int* __restrict__ src, const int* __restrict__ dst,
                         const float* __restrict__ h, float* __restrict__ agg) {
    int i = blockIdx.x * blockDim.x + threadIdx.x;
    if (i >= N_EDGES) return;
    int s = src[i];
    int d = dst[i];
    const float* hs = h + (long)s * F;
    float* ad = agg + (long)d * F;
#pragma unroll
    for (int f = 0; f < F; ++f) {
        atomicAdd(&ad[f], hs[f]);
    }
}

// ---------------- per-node epilogue: relu(agg*inv @ wl^T + b + h @ wr^T) ----------------
template <int FIN, int FOUT>
__global__ void node_apply(const float* __restrict__ agg,
                           const float* __restrict__ hin,
                           const int* __restrict__ deg,
                           const float* __restrict__ wl,
                           const float* __restrict__ bl,
                           const float* __restrict__ wr,
                           float* __restrict__ hout) {
    __shared__ float s_wl[FOUT * FIN];
    __shared__ float s_wr[FOUT * FIN];
    __shared__ float s_b[FOUT];
    for (int t = threadIdx.x; t < FOUT * FIN; t += blockDim.x) {
        s_wl[t] = wl[t];
        s_wr[t] = wr[t];
    }
    for (int t = threadIdx.x; t < FOUT; t += blockDim.x) s_b[t] = bl[t];
    __syncthreads();

    int i = blockIdx.x * blockDim.x + threadIdx.x;
    if (i >= N_NODES) return;

    float inv = 1.0f / fmaxf((float)deg[i], 1.0f);
    float a[FIN], xv[FIN];
#pragma unroll
    for (int k = 0; k < FIN; ++k) {
        a[k]  = agg[(long)i * FIN + k] * inv;
        xv[k] = hin[(long)i * FIN + k];
    }
#pragma unroll
    for (int j = 0; j < FOUT; ++j) {
        float acc = s_b[j];
#pragma unroll
        for (int k = 0; k < FIN; ++k) {
            acc += s_wl[j * FIN + k] * a[k] + s_wr[j * FIN + k] * xv[k];
        }
        acc = fmaxf(acc, 0.0f);  // all three conv layers are relu'd
        hout[(long)i * FOUT + j] = acc;
    }
}

// ---------------- layer 3 + classifier fused ----------------
__global__ void node_final(const float* __restrict__ agg,
                           const float* __restrict__ hin,
                           const int* __restrict__ deg,
                           const float* __restrict__ w3l,
                           const float* __restrict__ b3,
                           const float* __restrict__ w3r,
                           const float* __restrict__ wc,
                           const float* __restrict__ bc,
                           float* __restrict__ out) {
    __shared__ float s_wl[20 * 20];
    __shared__ float s_wr[20 * 20];
    __shared__ float s_b[20];
    __shared__ float s_wc[8 * 20];
    __shared__ float s_bc[8];
    for (int t = threadIdx.x; t < 400; t += blockDim.x) {
        s_wl[t] = w3l[t];
        s_wr[t] = w3r[t];
    }
    for (int t = threadIdx.x; t < 160; t += blockDim.x) s_wc[t] = wc[t];
    for (int t = threadIdx.x; t < 20; t += blockDim.x) s_b[t] = b3[t];
    for (int t = threadIdx.x; t < 8; t += blockDim.x) s_bc[t] = bc[t];
    __syncthreads();

    int i = blockIdx.x * blockDim.x + threadIdx.x;
    if (i >= N_NODES) return;

    float inv = 1.0f / fmaxf((float)deg[i], 1.0f);
    float a[20], xv[20];
#pragma unroll
    for (int k = 0; k < 20; ++k) {
        a[k]  = agg[(long)i * 20 + k] * inv;
        xv[k] = hin[(long)i * 20 + k];
    }
    float h3[20];
#pragma unroll
    for (int j = 0; j < 20; ++j) {
        float acc = s_b[j];
#pragma unroll
        for (int k = 0; k < 20; ++k) {
            acc += s_wl[j * 20 + k] * a[k] + s_wr[j * 20 + k] * xv[k];
        }
        h3[j] = fmaxf(acc, 0.0f);
    }
#pragma unroll
    for (int j = 0; j < 8; ++j) {
        float acc = s_bc[j];
#pragma unroll
        for (int k = 0; k < 20; ++k) {
            acc += s_wc[j * 20 + k] * h3[k];
        }
        out[(long)i * 8 + j] = acc;
    }
}

extern "C" void kernel_launch(void* const* d_in, const int* in_sizes, int n_in,
                              void* d_out, int out_size, void* d_ws, size_t ws_size,
                              hipStream_t stream) {
    const float* x   = (const float*)d_in[0];
    const int*   ei  = (const int*)d_in[1];   // [2, E] row-major: src then dst
    const float* w1l = (const float*)d_in[2];
    const float* b1  = (const float*)d_in[3];
    const float* w1r = (const float*)d_in[4];
    const float* w2l = (const float*)d_in[5];
    const float* b2  = (const float*)d_in[6];
    const float* w2r = (const float*)d_in[7];
    const float* w3l = (const float*)d_in[8];
    const float* b3  = (const float*)d_in[9];
    const float* w3r = (const float*)d_in[10];
    const float* wc  = (const float*)d_in[11];
    const float* bc  = (const float*)d_in[12];
    float* out = (float*)d_out;

    const int* src = ei;
    const int* dst = ei + N_EDGES;

    // workspace layout (bytes): deg[2MB] | agg[40MB] | h1[20MB] | h2[40MB]
    char* ws = (char*)d_ws;
    int*   deg = (int*)ws;
    float* agg = (float*)(ws + 2000000);
    float* h1  = (float*)(ws + 42000000);
    float* h2  = (float*)(ws + 62000000);

    const int BT = 256;
    dim3 blk(BT);
    dim3 egrid((N_EDGES + BT - 1) / BT);
    dim3 ngrid((N_NODES + BT - 1) / BT);

    // degrees (shared by all layers)
    hipMemsetAsync(deg, 0, (size_t)N_NODES * sizeof(int), stream);
    deg_kernel<<<egrid, blk, 0, stream>>>(dst, deg);

    // layer 1: 4 -> 10
    hipMemsetAsync(agg, 0, (size_t)N_NODES * 4 * sizeof(float), stream);
    edge_agg<4><<<egrid, blk, 0, stream>>>(src, dst, x, agg);
    node_apply<4, 10><<<ngrid, blk, 0, stream>>>(agg, x, deg, w1l, b1, w1r, h1);

    // layer 2: 10 -> 20
    hipMemsetAsync(agg, 0, (size_t)N_NODES * 10 * sizeof(float), stream);
    edge_agg<10><<<egrid, blk, 0, stream>>>(src, dst, h1, agg);
    node_apply<10, 20><<<ngrid, blk, 0, stream>>>(agg, h1, deg, w2l, b2, w2r, h2);

    // layer 3: 20 -> 20, fused with classifier 20 -> 8
    hipMemsetAsync(agg, 0, (size_t)N_NODES * 20 * sizeof(float), stream);
    edge_agg<20><<<egrid, blk, 0, stream>>>(src, dst, h2, agg);
    node_final<<<ngrid, blk, 0, stream>>>(agg, h2, deg, w3l, b3, w3r, wc, bc, out);
}

// Round 2
// 3136.152 us; speedup vs baseline: 8.9331x; 8.9331x over previous
//
#include <hip/hip_runtime.h>

#define N_NODES 500000
#define N_EDGES 16000000
#define NB 1954  // ceil(N_NODES / 256)

// ============================================================================
// Path A: sort-by-dst + gather (no float atomics)
// ============================================================================

__global__ void deg_kernel(const int* __restrict__ dst, int* __restrict__ deg) {
    int i = blockIdx.x * blockDim.x + threadIdx.x;
    if (i < N_EDGES) atomicAdd(&deg[dst[i]], 1);
}

// per-block exclusive scan of deg -> off, block totals -> bsum
__global__ void scan_block(const int* __restrict__ deg, int* __restrict__ off,
                           int* __restrict__ bsum) {
    __shared__ int s[256];
    int t = threadIdx.x;
    int i = blockIdx.x * 256 + t;
    int v = (i < N_NODES) ? deg[i] : 0;
    s[t] = v;
    __syncthreads();
    for (int o = 1; o < 256; o <<= 1) {
        int x = (t >= o) ? s[t - o] : 0;
        __syncthreads();
        s[t] += x;
        __syncthreads();
    }
    if (i < N_NODES) off[i] = s[t] - v;  // exclusive
    if (t == 255) bsum[blockIdx.x] = s[255];
}

// exclusive scan of NB block sums, single block (256 thr x 8 elems)
__global__ void scan_bsum(int* __restrict__ bsum) {
    __shared__ int s[256];
    int t = threadIdx.x;
    int base = t * 8;
    int loc[8];
    int sum = 0;
#pragma unroll
    for (int j = 0; j < 8; ++j) {
        int idx = base + j;
        int v = (idx < NB) ? bsum[idx] : 0;
        loc[j] = sum;
        sum += v;
    }
    s[t] = sum;
    __syncthreads();
    for (int o = 1; o < 256; o <<= 1) {
        int x = (t >= o) ? s[t - o] : 0;
        __syncthreads();
        s[t] += x;
        __syncthreads();
    }
    int excl = s[t] - sum;
#pragma unroll
    for (int j = 0; j < 8; ++j) {
        int idx = base + j;
        if (idx < NB) bsum[idx] = excl + loc[j];
    }
}

// off[i] += bsum[block]; cursor[i] = off[i]; off[N] = E
__global__ void scan_add(int* __restrict__ off, const int* __restrict__ bsum,
                         int* __restrict__ cursor) {
    int i = blockIdx.x * 256 + threadIdx.x;
    if (i < N_NODES) {
        int o = off[i] + bsum[blockIdx.x];
        off[i] = o;
        cursor[i] = o;
    }
    if (i == 0 && blockIdx.x == 0) off[N_NODES] = N_EDGES;
}

__global__ void scatter_kernel(const int* __restrict__ src, const int* __restrict__ dst,
                               int* __restrict__ cursor, int* __restrict__ ssrc) {
    int i = blockIdx.x * blockDim.x + threadIdx.x;
    if (i >= N_EDGES) return;
    int pos = atomicAdd(&cursor[dst[i]], 1);
    ssrc[pos] = src[i];
}

// Fused gather-mean + linear epilogue + relu.
// FIN actual input feats, LD = ceil4(FIN) loaded feats, SIN/SOUT row strides (floats).
template <int FIN, int LD, int SIN, int FOUT, int SOUT>
__global__ void fused_sage(const int* __restrict__ off, const int* __restrict__ ssrc,
                           const float* __restrict__ hin,
                           const float* __restrict__ wl, const float* __restrict__ bl,
                           const float* __restrict__ wr, float* __restrict__ hout) {
    __shared__ float s_wl[FOUT * FIN];
    __shared__ float s_wr[FOUT * FIN];
    __shared__ float s_b[FOUT];
    for (int t = threadIdx.x; t < FOUT * FIN; t += 256) {
        s_wl[t] = wl[t];
        s_wr[t] = wr[t];
    }
    if (threadIdx.x < FOUT) s_b[threadIdx.x] = bl[threadIdx.x];
    __syncthreads();

    int i = blockIdx.x * 256 + threadIdx.x;
    if (i >= N_NODES) return;

    int b = off[i], e = off[i + 1];
    constexpr int NQ = LD / 4;
    constexpr int UN = (NQ >= 4) ? 2 : 4;  // edges in flight (VGPR vs MLP tradeoff)

    float acc[LD];
#pragma unroll
    for (int k = 0; k < LD; ++k) acc[k] = 0.f;

    int k = b;
    for (; k + UN - 1 < e; k += UN) {
        int sidx[UN];
#pragma unroll
        for (int u = 0; u < UN; ++u) sidx[u] = ssrc[k + u];
        float4 v[UN][NQ];
#pragma unroll
        for (int u = 0; u < UN; ++u) {
            const float4* p = (const float4*)(hin + (long)sidx[u] * SIN);
#pragma unroll
            for (int q = 0; q < NQ; ++q) v[u][q] = p[q];
        }
#pragma unroll
        for (int u = 0; u < UN; ++u) {
#pragma unroll
            for (int q = 0; q < NQ; ++q) {
                acc[q * 4 + 0] += v[u][q].x;
                acc[q * 4 + 1] += v[u][q].y;
                acc[q * 4 + 2] += v[u][q].z;
                acc[q * 4 + 3] += v[u][q].w;
            }
        }
    }
    for (; k < e; ++k) {
        int s = ssrc[k];
        const float4* p = (const float4*)(hin + (long)s * SIN);
#pragma unroll
        for (int q = 0; q < NQ; ++q) {
            float4 vv = p[q];
            acc[q * 4 + 0] += vv.x;
            acc[q * 4 + 1] += vv.y;
            acc[q * 4 + 2] += vv.z;
            acc[q * 4 + 3] += vv.w;
        }
    }

    float inv = 1.f / fmaxf((float)(e - b), 1.f);
#pragma unroll
    for (int q = 0; q < FIN; ++q) acc[q] *= inv;

    float xv[LD];
    const float4* xp = (const float4*)(hin + (long)i * SIN);
#pragma unroll
    for (int q = 0; q < NQ; ++q) {
        float4 vv = xp[q];
        xv[q * 4 + 0] = vv.x;
        xv[q * 4 + 1] = vv.y;
        xv[q * 4 + 2] = vv.z;
        xv[q * 4 + 3] = vv.w;
    }

#pragma unroll
    for (int j = 0; j < FOUT; ++j) {
        float r = s_b[j];
#pragma unroll
        for (int kk = 0; kk < FIN; ++kk) {
            r += s_wl[j * FIN + kk] * acc[kk] + s_wr[j * FIN + kk] * xv[kk];
        }
        hout[(long)i * SOUT + j] = fmaxf(r, 0.f);
    }
}

// layer 3 (20->20, relu) + classifier (20->8) fused
__global__ void fused_final(const int* __restrict__ off, const int* __restrict__ ssrc,
                            const float* __restrict__ hin,
                            const float* __restrict__ w3l, const float* __restrict__ b3,
                            const float* __restrict__ w3r,
                            const float* __restrict__ wc, const float* __restrict__ bc,
                            float* __restrict__ out) {
    __shared__ float s_wl[400];
    __shared__ float s_wr[400];
    __shared__ float s_b[20];
    __shared__ float s_wc[160];
    __shared__ float s_bc[8];
    for (int t = threadIdx.x; t < 400; t += 256) {
        s_wl[t] = w3l[t];
        s_wr[t] = w3r[t];
    }
    if (threadIdx.x < 160) s_wc[threadIdx.x] = wc[threadIdx.x];
    if (threadIdx.x < 20) s_b[threadIdx.x] = b3[threadIdx.x];
    if (threadIdx.x >= 32 && threadIdx.x < 40) s_bc[threadIdx.x - 32] = bc[threadIdx.x - 32];
    __syncthreads();

    int i = blockIdx.x * 256 + threadIdx.x;
    if (i >= N_NODES) return;

    int b = off[i], e = off[i + 1];
    constexpr int NQ = 5;  // 20 floats
    constexpr int UN = 2;

    float acc[20];
#pragma unroll
    for (int k = 0; k < 20; ++k) acc[k] = 0.f;

    int k = b;
    for (; k + UN - 1 < e; k += UN) {
        int sidx[UN];
#pragma unroll
        for (int u = 0; u < UN; ++u) sidx[u] = ssrc[k + u];
        float4 v[UN][NQ];
#pragma unroll
        for (int u = 0; u < UN; ++u) {
            const float4* p = (const float4*)(hin + (long)sidx[u] * 20);
#pragma unroll
            for (int q = 0; q < NQ; ++q) v[u][q] = p[q];
        }
#pragma unroll
        for (int u = 0; u < UN; ++u) {
#pragma unroll
            for (int q = 0; q < NQ; ++q) {
                acc[q * 4 + 0] += v[u][q].x;
                acc[q * 4 + 1] += v[u][q].y;
                acc[q * 4 + 2] += v[u][q].z;
                acc[q * 4 + 3] += v[u][q].w;
            }
        }
    }
    for (; k < e; ++k) {
        int s = ssrc[k];
        const float4* p = (const float4*)(hin + (long)s * 20);
#pragma unroll
        for (int q = 0; q < NQ; ++q) {
            float4 vv = p[q];
            acc[q * 4 + 0] += vv.x;
            acc[q * 4 + 1] += vv.y;
            acc[q * 4 + 2] += vv.z;
            acc[q * 4 + 3] += vv.w;
        }
    }

    float inv = 1.f / fmaxf((float)(e - b), 1.f);
#pragma unroll
    for (int q = 0; q < 20; ++q) acc[q] *= inv;

    float xv[20];
    const float4* xp = (const float4*)(hin + (long)i * 20);
#pragma unroll
    for (int q = 0; q < NQ; ++q) {
        float4 vv = xp[q];
        xv[q * 4 + 0] = vv.x;
        xv[q * 4 + 1] = vv.y;
        xv[q * 4 + 2] = vv.z;
        xv[q * 4 + 3] = vv.w;
    }

    float h3[20];
#pragma unroll
    for (int j = 0; j < 20; ++j) {
        float r = s_b[j];
#pragma unroll
        for (int kk = 0; kk < 20; ++kk) {
            r += s_wl[j * 20 + kk] * acc[kk] + s_wr[j * 20 + kk] * xv[kk];
        }
        h3[j] = fmaxf(r, 0.f);
    }
#pragma unroll
    for (int j = 0; j < 8; ++j) {
        float r = s_bc[j];
#pragma unroll
        for (int kk = 0; kk < 20; ++kk) {
            r += s_wc[j * 20 + kk] * h3[kk];
        }
        out[(long)i * 8 + j] = r;
    }
}

// ============================================================================
// Path B (fallback, ws_size < 132 MB): original float-atomic version
// ============================================================================

template <int F>
__global__ void edge_agg(const int* __restrict__ src, const int* __restrict__ dst,
                         const float* __restrict__ h, float* __restrict__ agg) {
    int i = blockIdx.x * blockDim.x + threadIdx.x;
    if (i >= N_EDGES) return;
    int s = src[i];
    int d = dst[i];
    const float* hs = h + (long)s * F;
    float* ad = agg + (long)d * F;
#pragma unroll
    for (int f = 0; f < F; ++f) atomicAdd(&ad[f], hs[f]);
}

template <int FIN, int FOUT>
__global__ void node_apply(const float* __restrict__ agg, const float* __restrict__ hin,
                           const int* __restrict__ deg, const float* __restrict__ wl,
                           const float* __restrict__ bl, const float* __restrict__ wr,
                           float* __restrict__ hout) {
    __shared__ float s_wl[FOUT * FIN];
    __shared__ float s_wr[FOUT * FIN];
    __shared__ float s_b[FOUT];
    for (int t = threadIdx.x; t < FOUT * FIN; t += blockDim.x) {
        s_wl[t] = wl[t];
        s_wr[t] = wr[t];
    }
    for (int t = threadIdx.x; t < FOUT; t += blockDim.x) s_b[t] = bl[t];
    __syncthreads();
    int i = blockIdx.x * blockDim.x + threadIdx.x;
    if (i >= N_NODES) return;
    float inv = 1.0f / fmaxf((float)deg[i], 1.0f);
    float a[FIN], xv[FIN];
#pragma unroll
    for (int kk = 0; kk < FIN; ++kk) {
        a[kk] = agg[(long)i * FIN + kk] * inv;
        xv[kk] = hin[(long)i * FIN + kk];
    }
#pragma unroll
    for (int j = 0; j < FOUT; ++j) {
        float r = s_b[j];
#pragma unroll
        for (int kk = 0; kk < FIN; ++kk) r += s_wl[j * FIN + kk] * a[kk] + s_wr[j * FIN + kk] * xv[kk];
        hout[(long)i * FOUT + j] = fmaxf(r, 0.f);
    }
}

__global__ void node_final_old(const float* __restrict__ agg, const float* __restrict__ hin,
                               const int* __restrict__ deg, const float* __restrict__ w3l,
                               const float* __restrict__ b3, const float* __restrict__ w3r,
                               const float* __restrict__ wc, const float* __restrict__ bc,
                               float* __restrict__ out) {
    __shared__ float s_wl[400];
    __shared__ float s_wr[400];
    __shared__ float s_b[20];
    __shared__ float s_wc[160];
    __shared__ float s_bc[8];
    for (int t = threadIdx.x; t < 400; t += blockDim.x) {
        s_wl[t] = w3l[t];
        s_wr[t] = w3r[t];
    }
    for (int t = threadIdx.x; t < 160; t += blockDim.x) s_wc[t] = wc[t];
    for (int t = threadIdx.x; t < 20; t += blockDim.x) s_b[t] = b3[t];
    for (int t = threadIdx.x; t < 8; t += blockDim.x) s_bc[t] = bc[t];
    __syncthreads();
    int i = blockIdx.x * blockDim.x + threadIdx.x;
    if (i >= N_NODES) return;
    float inv = 1.0f / fmaxf((float)deg[i], 1.0f);
    float a[20], xv[20];
#pragma unroll
    for (int kk = 0; kk < 20; ++kk) {
        a[kk] = agg[(long)i * 20 + kk] * inv;
        xv[kk] = hin[(long)i * 20 + kk];
    }
    float h3[20];
#pragma unroll
    for (int j = 0; j < 20; ++j) {
        float r = s_b[j];
#pragma unroll
        for (int kk = 0; kk < 20; ++kk) r += s_wl[j * 20 + kk] * a[kk] + s_wr[j * 20 + kk] * xv[kk];
        h3[j] = fmaxf(r, 0.f);
    }
#pragma unroll
    for (int j = 0; j < 8; ++j) {
        float r = s_bc[j];
#pragma unroll
        for (int kk = 0; kk < 20; ++kk) r += s_wc[j * 20 + kk] * h3[kk];
        out[(long)i * 8 + j] = r;
    }
}

// ============================================================================

extern "C" void kernel_launch(void* const* d_in, const int* in_sizes, int n_in,
                              void* d_out, int out_size, void* d_ws, size_t ws_size,
                              hipStream_t stream) {
    const float* x = (const float*)d_in[0];
    const int* ei = (const int*)d_in[1];  // [2, E]: src row then dst row
    const float* w1l = (const float*)d_in[2];
    const float* b1 = (const float*)d_in[3];
    const float* w1r = (const float*)d_in[4];
    const float* w2l = (const float*)d_in[5];
    const float* b2 = (const float*)d_in[6];
    const float* w2r = (const float*)d_in[7];
    const float* w3l = (const float*)d_in[8];
    const float* b3 = (const float*)d_in[9];
    const float* w3r = (const float*)d_in[10];
    const float* wc = (const float*)d_in[11];
    const float* bc = (const float*)d_in[12];
    float* out = (float*)d_out;

    const int* src = ei;
    const int* dst = ei + N_EDGES;

    const int BT = 256;
    dim3 blk(BT);
    dim3 egrid((N_EDGES + BT - 1) / BT);
    dim3 ngrid(NB);

    // ---- Path A layout (bytes):
    // deg/cursor [0, 2,000,000)
    // off        [2,000,000, 4,000,004)
    // bsum       [4,000,016, 4,007,832)
    // ssrc       [4,016,000, 68,016,000)            16M ints
    // h1         [68,016,000, 92,016,000)           500K x 12 floats (10 used)
    // h2         [92,016,000, 132,016,000)          500K x 20 floats
    const size_t NEED_A = 132016000;

    if (ws_size >= NEED_A) {
        char* ws = (char*)d_ws;
        int* deg = (int*)ws;  // reused as cursor after scan
        int* off = (int*)(ws + 2000000);
        int* bsum = (int*)(ws + 4000016);
        int* ssrc = (int*)(ws + 4016000);
        float* h1 = (float*)(ws + 68016000);
        float* h2 = (float*)(ws + 92016000);

        hipMemsetAsync(deg, 0, (size_t)N_NODES * sizeof(int), stream);
        deg_kernel<<<egrid, blk, 0, stream>>>(dst, deg);
        scan_block<<<ngrid, blk, 0, stream>>>(deg, off, bsum);
        scan_bsum<<<1, blk, 0, stream>>>(bsum);
        scan_add<<<ngrid, blk, 0, stream>>>(off, bsum, deg);
        scatter_kernel<<<egrid, blk, 0, stream>>>(src, dst, deg, ssrc);

        fused_sage<4, 4, 4, 10, 12><<<ngrid, blk, 0, stream>>>(off, ssrc, x, w1l, b1, w1r, h1);
        fused_sage<10, 12, 12, 20, 20><<<ngrid, blk, 0, stream>>>(off, ssrc, h1, w2l, b2, w2r, h2);
        fused_final<<<ngrid, blk, 0, stream>>>(off, ssrc, h2, w3l, b3, w3r, wc, bc, out);
    } else {
        // fallback: float-atomic path (needs 102 MB)
        char* ws = (char*)d_ws;
        int* deg = (int*)ws;
        float* agg = (float*)(ws + 2000000);
        float* h1 = (float*)(ws + 42000000);
        float* h2 = (float*)(ws + 62000000);

        hipMemsetAsync(deg, 0, (size_t)N_NODES * sizeof(int), stream);
        deg_kernel<<<egrid, blk, 0, stream>>>(dst, deg);

        hipMemsetAsync(agg, 0, (size_t)N_NODES * 4 * sizeof(float), stream);
        edge_agg<4><<<egrid, blk, 0, stream>>>(src, dst, x, agg);
        node_apply<4, 10><<<ngrid, blk, 0, stream>>>(agg, x, deg, w1l, b1, w1r, h1);

        hipMemsetAsync(agg, 0, (size_t)N_NODES * 10 * sizeof(float), stream);
        edge_agg<10><<<egrid, blk, 0, stream>>>(src, dst, h1, agg);
        node_apply<10, 20><<<ngrid, blk, 0, stream>>>(agg, h1, deg, w2l, b2, w2r, h2);

        hipMemsetAsync(agg, 0, (size_t)N_NODES * 20 * sizeof(float), stream);
        edge_agg<20><<<egrid, blk, 0, stream>>>(src, dst, h2, agg);
        node_final_old<<<ngrid, blk, 0, stream>>>(agg, h2, deg, w3l, b3, w3r, wc, bc, out);
    }
}

// Round 3
// 1901.918 us; speedup vs baseline: 14.7302x; 1.6489x over previous
//
#include <hip/hip_runtime.h>

#define N_NODES 500000
#define N_EDGES 16000000
#define NB 1954          // ceil(N_NODES/256)
#define NPB_LOG 9
#define NPB 512          // nodes per bucket
#define NBUCK 977        // ceil(N_NODES/NPB)
#define NBUCK_PAD 1024
#define CH 32768         // edges per bucket_scatter block
#define NSB 489          // ceil(N_EDGES/CH)

// ============================================================================
// Path A v2: two-level counting sort (LDS atomics) + fused gather layers
// ============================================================================

// coarse histogram of dst>>9 into ghist (= gcur array, must be zeroed)
__global__ void bucket_hist(const int* __restrict__ dst, int* __restrict__ ghist) {
    __shared__ int lhist[NBUCK_PAD];
    for (int t = threadIdx.x; t < NBUCK_PAD; t += 256) lhist[t] = 0;
    __syncthreads();
    int stride = gridDim.x * 256;
    for (int i = blockIdx.x * 256 + threadIdx.x; i < N_EDGES; i += stride) {
        atomicAdd(&lhist[dst[i] >> NPB_LOG], 1);
    }
    __syncthreads();
    for (int t = threadIdx.x; t < NBUCK_PAD; t += 256) {
        int c = lhist[t];
        if (c) atomicAdd(&ghist[t], c);
    }
}

// exclusive scan of 1024 bucket counts; bbase[b]=excl, gcur[b]=excl, bbase[1024]=total
__global__ void bucket_scan(int* __restrict__ gcur, int* __restrict__ bbase) {
    __shared__ int s[256];
    int t = threadIdx.x;
    int v[4], sum = 0, loc[4];
#pragma unroll
    for (int j = 0; j < 4; ++j) {
        v[j] = gcur[t * 4 + j];
        loc[j] = sum;
        sum += v[j];
    }
    s[t] = sum;
    __syncthreads();
    for (int o = 1; o < 256; o <<= 1) {
        int x = (t >= o) ? s[t - o] : 0;
        __syncthreads();
        s[t] += x;
        __syncthreads();
    }
    int excl = s[t] - sum;
#pragma unroll
    for (int j = 0; j < 4; ++j) {
        int e = excl + loc[j];
        bbase[t * 4 + j] = e;
        gcur[t * 4 + j] = e;
    }
    if (t == 255) bbase[NBUCK_PAD] = s[255];
}

// bucket edges: P[pos] = (dst&511)<<19 | src, grouped by bucket = dst>>9
__global__ void bucket_scatter(const int* __restrict__ src, const int* __restrict__ dst,
                               int* __restrict__ gcur, int* __restrict__ P) {
    __shared__ int lhist[NBUCK_PAD];
    __shared__ int lcur[NBUCK_PAD];
    for (int t = threadIdx.x; t < NBUCK_PAD; t += 256) lhist[t] = 0;
    __syncthreads();

    int e0 = blockIdx.x * CH;
    int e1 = min(e0 + CH, N_EDGES);

    for (int i = e0 + threadIdx.x; i < e1; i += 256) {
        atomicAdd(&lhist[dst[i] >> NPB_LOG], 1);
    }
    __syncthreads();
    for (int t = threadIdx.x; t < NBUCK_PAD; t += 256) {
        int c = lhist[t];
        lcur[t] = c ? atomicAdd(&gcur[t], c) : 0;
    }
    __syncthreads();
    for (int i = e0 + threadIdx.x; i < e1; i += 256) {
        int d = dst[i];
        int s = src[i];
        int b = d >> NPB_LOG;
        int pos = atomicAdd(&lcur[b], 1);
        P[pos] = ((d & (NPB - 1)) << 19) | s;
    }
}

// per-bucket counting sort: writes off[] (global CSR offsets) and sorted src S[]
__global__ void fine_sort(const int* __restrict__ P, const int* __restrict__ bbase,
                          int* __restrict__ off, int* __restrict__ S) {
    __shared__ int lhist[NPB];
    __shared__ int lexcl[NPB];
    __shared__ int sscan[256];
    int t = threadIdx.x;
    int b = blockIdx.x;
    int bb = bbase[b];
    int be = bbase[b + 1];
    int node0 = b << NPB_LOG;

    lhist[t] = 0;
    lhist[t + 256] = 0;
    __syncthreads();
    for (int j = bb + t; j < be; j += 256) {
        atomicAdd(&lhist[P[j] >> 19], 1);
    }
    __syncthreads();

    // exclusive scan of 512 via pair-sum + Hillis-Steele(256)
    int a0 = lhist[2 * t], a1 = lhist[2 * t + 1];
    int ps = a0 + a1;
    sscan[t] = ps;
    __syncthreads();
    for (int o = 1; o < 256; o <<= 1) {
        int x = (t >= o) ? sscan[t - o] : 0;
        __syncthreads();
        sscan[t] += x;
        __syncthreads();
    }
    int pe = sscan[t] - ps;
    lexcl[2 * t] = pe;
    lexcl[2 * t + 1] = pe + a0;
    __syncthreads();

    // write off + init cursors (reuse lhist as cursor)
#pragma unroll
    for (int j = 0; j < 2; ++j) {
        int idx = t + j * 256;
        int ng = node0 + idx;
        if (ng < N_NODES) off[ng] = bb + lexcl[idx];
        lhist[idx] = lexcl[idx];
    }
    if (b == NBUCK - 1 && t == 0) off[N_NODES] = N_EDGES;
    __syncthreads();

    for (int j = bb + t; j < be; j += 256) {
        int p = P[j];
        int n = p >> 19;
        int s = p & 0x7FFFF;
        int pos = atomicAdd(&lhist[n], 1);
        S[bb + pos] = s;
    }
}

// Fused gather-mean + linear epilogue + relu.
template <int FIN, int LD, int SIN, int FOUT, int SOUT>
__global__ void fused_sage(const int* __restrict__ off, const int* __restrict__ ssrc,
                           const float* __restrict__ hin,
                           const float* __restrict__ wl, const float* __restrict__ bl,
                           const float* __restrict__ wr, float* __restrict__ hout) {
    __shared__ float s_wl[FOUT * FIN];
    __shared__ float s_wr[FOUT * FIN];
    __shared__ float s_b[FOUT];
    for (int t = threadIdx.x; t < FOUT * FIN; t += 256) {
        s_wl[t] = wl[t];
        s_wr[t] = wr[t];
    }
    if (threadIdx.x < FOUT) s_b[threadIdx.x] = bl[threadIdx.x];
    __syncthreads();

    int i = blockIdx.x * 256 + threadIdx.x;
    if (i >= N_NODES) return;

    int b = off[i], e = off[i + 1];
    constexpr int NQ = LD / 4;
    constexpr int UN = (NQ >= 5) ? 3 : 4;

    float acc[LD];
#pragma unroll
    for (int k = 0; k < LD; ++k) acc[k] = 0.f;

    int k = b;
    for (; k + UN - 1 < e; k += UN) {
        int sidx[UN];
#pragma unroll
        for (int u = 0; u < UN; ++u) sidx[u] = ssrc[k + u];
        float4 v[UN][NQ];
#pragma unroll
        for (int u = 0; u < UN; ++u) {
            const float4* p = (const float4*)(hin + (long)sidx[u] * SIN);
#pragma unroll
            for (int q = 0; q < NQ; ++q) v[u][q] = p[q];
        }
#pragma unroll
        for (int u = 0; u < UN; ++u) {
#pragma unroll
            for (int q = 0; q < NQ; ++q) {
                acc[q * 4 + 0] += v[u][q].x;
                acc[q * 4 + 1] += v[u][q].y;
                acc[q * 4 + 2] += v[u][q].z;
                acc[q * 4 + 3] += v[u][q].w;
            }
        }
    }
    for (; k < e; ++k) {
        int s = ssrc[k];
        const float4* p = (const float4*)(hin + (long)s * SIN);
#pragma unroll
        for (int q = 0; q < NQ; ++q) {
            float4 vv = p[q];
            acc[q * 4 + 0] += vv.x;
            acc[q * 4 + 1] += vv.y;
            acc[q * 4 + 2] += vv.z;
            acc[q * 4 + 3] += vv.w;
        }
    }

    float inv = 1.f / fmaxf((float)(e - b), 1.f);
#pragma unroll
    for (int q = 0; q < FIN; ++q) acc[q] *= inv;

    float xv[LD];
    const float4* xp = (const float4*)(hin + (long)i * SIN);
#pragma unroll
    for (int q = 0; q < NQ; ++q) {
        float4 vv = xp[q];
        xv[q * 4 + 0] = vv.x;
        xv[q * 4 + 1] = vv.y;
        xv[q * 4 + 2] = vv.z;
        xv[q * 4 + 3] = vv.w;
    }

#pragma unroll
    for (int j = 0; j < FOUT; ++j) {
        float r = s_b[j];
#pragma unroll
        for (int kk = 0; kk < FIN; ++kk) {
            r += s_wl[j * FIN + kk] * acc[kk] + s_wr[j * FIN + kk] * xv[kk];
        }
        hout[(long)i * SOUT + j] = fmaxf(r, 0.f);
    }
}

// layer 3 (20->20, relu) + classifier (20->8) fused
__global__ void fused_final(const int* __restrict__ off, const int* __restrict__ ssrc,
                            const float* __restrict__ hin,
                            const float* __restrict__ w3l, const float* __restrict__ b3,
                            const float* __restrict__ w3r,
                            const float* __restrict__ wc, const float* __restrict__ bc,
                            float* __restrict__ out) {
    __shared__ float s_wl[400];
    __shared__ float s_wr[400];
    __shared__ float s_b[20];
    __shared__ float s_wc[160];
    __shared__ float s_bc[8];
    for (int t = threadIdx.x; t < 400; t += 256) {
        s_wl[t] = w3l[t];
        s_wr[t] = w3r[t];
    }
    if (threadIdx.x < 160) s_wc[threadIdx.x] = wc[threadIdx.x];
    if (threadIdx.x < 20) s_b[threadIdx.x] = b3[threadIdx.x];
    if (threadIdx.x >= 32 && threadIdx.x < 40) s_bc[threadIdx.x - 32] = bc[threadIdx.x - 32];
    __syncthreads();

    int i = blockIdx.x * 256 + threadIdx.x;
    if (i >= N_NODES) return;

    int b = off[i], e = off[i + 1];
    constexpr int NQ = 5;
    constexpr int UN = 3;

    float acc[20];
#pragma unroll
    for (int k = 0; k < 20; ++k) acc[k] = 0.f;

    int k = b;
    for (; k + UN - 1 < e; k += UN) {
        int sidx[UN];
#pragma unroll
        for (int u = 0; u < UN; ++u) sidx[u] = ssrc[k + u];
        float4 v[UN][NQ];
#pragma unroll
        for (int u = 0; u < UN; ++u) {
            const float4* p = (const float4*)(hin + (long)sidx[u] * 20);
#pragma unroll
            for (int q = 0; q < NQ; ++q) v[u][q] = p[q];
        }
#pragma unroll
        for (int u = 0; u < UN; ++u) {
#pragma unroll
            for (int q = 0; q < NQ; ++q) {
                acc[q * 4 + 0] += v[u][q].x;
                acc[q * 4 + 1] += v[u][q].y;
                acc[q * 4 + 2] += v[u][q].z;
                acc[q * 4 + 3] += v[u][q].w;
            }
        }
    }
    for (; k < e; ++k) {
        int s = ssrc[k];
        const float4* p = (const float4*)(hin + (long)s * 20);
#pragma unroll
        for (int q = 0; q < NQ; ++q) {
            float4 vv = p[q];
            acc[q * 4 + 0] += vv.x;
            acc[q * 4 + 1] += vv.y;
            acc[q * 4 + 2] += vv.z;
            acc[q * 4 + 3] += vv.w;
        }
    }

    float inv = 1.f / fmaxf((float)(e - b), 1.f);
#pragma unroll
    for (int q = 0; q < 20; ++q) acc[q] *= inv;

    float xv[20];
    const float4* xp = (const float4*)(hin + (long)i * 20);
#pragma unroll
    for (int q = 0; q < NQ; ++q) {
        float4 vv = xp[q];
        xv[q * 4 + 0] = vv.x;
        xv[q * 4 + 1] = vv.y;
        xv[q * 4 + 2] = vv.z;
        xv[q * 4 + 3] = vv.w;
    }

    float h3[20];
#pragma unroll
    for (int j = 0; j < 20; ++j) {
        float r = s_b[j];
#pragma unroll
        for (int kk = 0; kk < 20; ++kk) {
            r += s_wl[j * 20 + kk] * acc[kk] + s_wr[j * 20 + kk] * xv[kk];
        }
        h3[j] = fmaxf(r, 0.f);
    }
#pragma unroll
    for (int j = 0; j < 8; ++j) {
        float r = s_bc[j];
#pragma unroll
        for (int kk = 0; kk < 20; ++kk) {
            r += s_wc[j * 20 + kk] * h3[kk];
        }
        out[(long)i * 8 + j] = r;
    }
}

// ============================================================================
// Path B (fallback, small ws): float-atomic version
// ============================================================================

__global__ void deg_kernel(const int* __restrict__ dst, int* __restrict__ deg) {
    int i = blockIdx.x * blockDim.x + threadIdx.x;
    if (i < N_EDGES) atomicAdd(&deg[dst[i]], 1);
}

template <int F>
__global__ void edge_agg(const int* __restrict__ src, const int* __restrict__ dst,
                         const float* __restrict__ h, float* __restrict__ agg) {
    int i = blockIdx.x * blockDim.x + threadIdx.x;
    if (i >= N_EDGES) return;
    int s = src[i];
    int d = dst[i];
    const float* hs = h + (long)s * F;
    float* ad = agg + (long)d * F;
#pragma unroll
    for (int f = 0; f < F; ++f) atomicAdd(&ad[f], hs[f]);
}

template <int FIN, int FOUT>
__global__ void node_apply(const float* __restrict__ agg, const float* __restrict__ hin,
                           const int* __restrict__ deg, const float* __restrict__ wl,
                           const float* __restrict__ bl, const float* __restrict__ wr,
                           float* __restrict__ hout) {
    __shared__ float s_wl[FOUT * FIN];
    __shared__ float s_wr[FOUT * FIN];
    __shared__ float s_b[FOUT];
    for (int t = threadIdx.x; t < FOUT * FIN; t += blockDim.x) {
        s_wl[t] = wl[t];
        s_wr[t] = wr[t];
    }
    for (int t = threadIdx.x; t < FOUT; t += blockDim.x) s_b[t] = bl[t];
    __syncthreads();
    int i = blockIdx.x * blockDim.x + threadIdx.x;
    if (i >= N_NODES) return;
    float inv = 1.0f / fmaxf((float)deg[i], 1.0f);
    float a[FIN], xv[FIN];
#pragma unroll
    for (int kk = 0; kk < FIN; ++kk) {
        a[kk] = agg[(long)i * FIN + kk] * inv;
        xv[kk] = hin[(long)i * FIN + kk];
    }
#pragma unroll
    for (int j = 0; j < FOUT; ++j) {
        float r = s_b[j];
#pragma unroll
        for (int kk = 0; kk < FIN; ++kk) r += s_wl[j * FIN + kk] * a[kk] + s_wr[j * FIN + kk] * xv[kk];
        hout[(long)i * FOUT + j] = fmaxf(r, 0.f);
    }
}

__global__ void node_final_old(const float* __restrict__ agg, const float* __restrict__ hin,
                               const int* __restrict__ deg, const float* __restrict__ w3l,
                               const float* __restrict__ b3, const float* __restrict__ w3r,
                               const float* __restrict__ wc, const float* __restrict__ bc,
                               float* __restrict__ out) {
    __shared__ float s_wl[400];
    __shared__ float s_wr[400];
    __shared__ float s_b[20];
    __shared__ float s_wc[160];
    __shared__ float s_bc[8];
    for (int t = threadIdx.x; t < 400; t += blockDim.x) {
        s_wl[t] = w3l[t];
        s_wr[t] = w3r[t];
    }
    for (int t = threadIdx.x; t < 160; t += blockDim.x) s_wc[t] = wc[t];
    for (int t = threadIdx.x; t < 20; t += blockDim.x) s_b[t] = b3[t];
    for (int t = threadIdx.x; t < 8; t += blockDim.x) s_bc[t] = bc[t];
    __syncthreads();
    int i = blockIdx.x * blockDim.x + threadIdx.x;
    if (i >= N_NODES) return;
    float inv = 1.0f / fmaxf((float)deg[i], 1.0f);
    float a[20], xv[20];
#pragma unroll
    for (int kk = 0; kk < 20; ++kk) {
        a[kk] = agg[(long)i * 20 + kk] * inv;
        xv[kk] = hin[(long)i * 20 + kk];
    }
    float h3[20];
#pragma unroll
    for (int j = 0; j < 20; ++j) {
        float r = s_b[j];
#pragma unroll
        for (int kk = 0; kk < 20; ++kk) r += s_wl[j * 20 + kk] * a[kk] + s_wr[j * 20 + kk] * xv[kk];
        h3[j] = fmaxf(r, 0.f);
    }
#pragma unroll
    for (int j = 0; j < 8; ++j) {
        float r = s_bc[j];
#pragma unroll
        for (int kk = 0; kk < 20; ++kk) r += s_wc[j * 20 + kk] * h3[kk];
        out[(long)i * 8 + j] = r;
    }
}

// ============================================================================

extern "C" void kernel_launch(void* const* d_in, const int* in_sizes, int n_in,
                              void* d_out, int out_size, void* d_ws, size_t ws_size,
                              hipStream_t stream) {
    const float* x = (const float*)d_in[0];
    const int* ei = (const int*)d_in[1];  // [2, E]: src row then dst row
    const float* w1l = (const float*)d_in[2];
    const float* b1 = (const float*)d_in[3];
    const float* w1r = (const float*)d_in[4];
    const float* w2l = (const float*)d_in[5];
    const float* b2 = (const float*)d_in[6];
    const float* w2r = (const float*)d_in[7];
    const float* w3l = (const float*)d_in[8];
    const float* b3 = (const float*)d_in[9];
    const float* w3r = (const float*)d_in[10];
    const float* wc = (const float*)d_in[11];
    const float* bc = (const float*)d_in[12];
    float* out = (float*)d_out;

    const int* src = ei;
    const int* dst = ei + N_EDGES;

    const int BT = 256;
    dim3 blk(BT);
    dim3 egrid((N_EDGES + BT - 1) / BT);
    dim3 ngrid(NB);

    // ---- Path A v2 layout (bytes):
    // off   [0,          2,000,128)   500001 ints (padded)
    // bbase [2,000,128,  2,004,352)   1025 ints (padded)
    // gcur  [2,004,352,  2,008,448)   1024 ints
    // P     [2,008,576,  66,008,576)  16M packed ints; h1/h2 overlay after fine_sort
    // S     [66,008,576, 130,008,576) 16M sorted src
    const size_t NEED_A = 130008576;

    if (ws_size >= NEED_A) {
        char* ws = (char*)d_ws;
        int* off = (int*)ws;
        int* bbase = (int*)(ws + 2000128);
        int* gcur = (int*)(ws + 2004352);
        int* P = (int*)(ws + 2008576);
        int* S = (int*)(ws + 66008576);
        float* h1 = (float*)(ws + 2008576);              // overlays P (dead after fine_sort)
        float* h2 = (float*)(ws + 2008576 + 24000000);

        hipMemsetAsync(gcur, 0, NBUCK_PAD * sizeof(int), stream);
        bucket_hist<<<1024, blk, 0, stream>>>(dst, gcur);
        bucket_scan<<<1, blk, 0, stream>>>(gcur, bbase);
        bucket_scatter<<<NSB, blk, 0, stream>>>(src, dst, gcur, P);
        fine_sort<<<NBUCK, blk, 0, stream>>>(P, bbase, off, S);

        fused_sage<4, 4, 4, 10, 12><<<ngrid, blk, 0, stream>>>(off, S, x, w1l, b1, w1r, h1);
        fused_sage<10, 12, 12, 20, 20><<<ngrid, blk, 0, stream>>>(off, S, h1, w2l, b2, w2r, h2);
        fused_final<<<ngrid, blk, 0, stream>>>(off, S, h2, w3l, b3, w3r, wc, bc, out);
    } else {
        // fallback: float-atomic path (needs 102 MB)
        char* ws = (char*)d_ws;
        int* deg = (int*)ws;
        float* agg = (float*)(ws + 2000000);
        float* h1 = (float*)(ws + 42000000);
        float* h2 = (float*)(ws + 62000000);

        hipMemsetAsync(deg, 0, (size_t)N_NODES * sizeof(int), stream);
        deg_kernel<<<egrid, blk, 0, stream>>>(dst, deg);

        hipMemsetAsync(agg, 0, (size_t)N_NODES * 4 * sizeof(float), stream);
        edge_agg<4><<<egrid, blk, 0, stream>>>(src, dst, x, agg);
        node_apply<4, 10><<<ngrid, blk, 0, stream>>>(agg, x, deg, w1l, b1, w1r, h1);

        hipMemsetAsync(agg, 0, (size_t)N_NODES * 10 * sizeof(float), stream);
        edge_agg<10><<<egrid, blk, 0, stream>>>(src, dst, h1, agg);
        node_apply<10, 20><<<ngrid, blk, 0, stream>>>(agg, h1, deg, w2l, b2, w2r, h2);

        hipMemsetAsync(agg, 0, (size_t)N_NODES * 20 * sizeof(float), stream);
        edge_agg<20><<<egrid, blk, 0, stream>>>(src, dst, h2, agg);
        node_final_old<<<ngrid, blk, 0, stream>>>(agg, h2, deg, w3l, b3, w3r, wc, bc, out);
    }
}